// Round 5
// baseline (442.520 us; speedup 1.0000x reference)
//
#include <hip/hip_runtime.h>

// GCN 2-layer + edge dot decoder. Dims fixed: in=512, hid=128, out=64.
#define IN_C  512
#define HID_C 128
#define OUT_C 64

using short8 = __attribute__((ext_vector_type(8))) short;   // 8 bf16
using floatx4 = __attribute__((ext_vector_type(4))) float;  // mfma acc

__device__ inline unsigned short f2bf(float f) {  // RNE
    unsigned u = __builtin_bit_cast(unsigned, f);
    u += 0x7FFFu + ((u >> 16) & 1u);
    return (unsigned short)(u >> 16);
}
__device__ inline float bf2f(unsigned short h) {
    unsigned u = ((unsigned)h) << 16;
    return __builtin_bit_cast(float, u);
}

// split 8 fp32 -> bf16 hi (truncate) + bf16 lo (RNE of exact residual)
__device__ inline void split8(const float4& u, const float4& v, short8& hi, short8& lo) {
    float f[8] = {u.x, u.y, u.z, u.w, v.x, v.y, v.z, v.w};
    union { unsigned short s[8]; short8 v8; } H, L;
#pragma unroll
    for (int j = 0; j < 8; ++j) {
        unsigned ub = __builtin_bit_cast(unsigned, f[j]);
        unsigned hb = ub & 0xFFFF0000u;
        H.s[j] = (unsigned short)(hb >> 16);
        L.s[j] = f2bf(f[j] - __builtin_bit_cast(float, hb));  // residual is exact fp32
    }
    hi = H.v8;
    lo = L.v8;
}

// ---------------- CSR build ----------------
__global__ void k_zero_int(int* __restrict__ p, int n) {
    int i = blockIdx.x * blockDim.x + threadIdx.x;
    if (i < n) p[i] = 0;
}

__global__ void k_count(const int* __restrict__ dst, int* __restrict__ cnt, int e) {
    int i = blockIdx.x * blockDim.x + threadIdx.x;
    if (i < e) atomicAdd(&cnt[dst[i]], 1);
}

__global__ void k_dinv(const int* __restrict__ cnt, float* __restrict__ dinv, int n) {
    int i = blockIdx.x * blockDim.x + threadIdx.x;
    if (i < n) dinv[i] = rsqrtf(1.0f + (float)cnt[i]);  // +1 self-loop
}

__global__ void k_blocksum(const int* __restrict__ cnt, int* __restrict__ bsum, int n) {
    __shared__ int sdata[256];
    int t = threadIdx.x;
    int i = blockIdx.x * 256 + t;
    sdata[t] = (i < n) ? cnt[i] : 0;
    __syncthreads();
    for (int s = 128; s > 0; s >>= 1) {
        if (t < s) sdata[t] += sdata[t + s];
        __syncthreads();
    }
    if (t == 0) bsum[blockIdx.x] = sdata[0];
}

__global__ void k_scanpartials(int* __restrict__ bsum, int nb) {
    __shared__ int sdata[256];
    int t = threadIdx.x;
    int orig = (t < nb) ? bsum[t] : 0;
    sdata[t] = orig;
    __syncthreads();
    for (int off = 1; off < 256; off <<= 1) {
        int v = (t >= off) ? sdata[t - off] : 0;
        __syncthreads();
        sdata[t] += v;
        __syncthreads();
    }
    if (t < nb) bsum[t] = sdata[t] - orig;  // exclusive
}

__global__ void k_scanfinal(const int* __restrict__ cnt, const int* __restrict__ bsum_ex,
                            int* __restrict__ row_ptr, int n, int e_total) {
    __shared__ int sdata[256];
    int t = threadIdx.x;
    int i = blockIdx.x * 256 + t;
    int orig = (i < n) ? cnt[i] : 0;
    sdata[t] = orig;
    __syncthreads();
    for (int off = 1; off < 256; off <<= 1) {
        int v = (t >= off) ? sdata[t - off] : 0;
        __syncthreads();
        sdata[t] += v;
        __syncthreads();
    }
    if (i < n) row_ptr[i] = sdata[t] - orig + bsum_ex[blockIdx.x];
    if (i == 0) row_ptr[n] = e_total;
}

__global__ void k_fill(const int* __restrict__ src, const int* __restrict__ dst,
                       const int* __restrict__ row_ptr, int* __restrict__ cur,
                       int* __restrict__ col, int e) {
    int i = blockIdx.x * blockDim.x + threadIdx.x;
    if (i < e) {
        int d = dst[i];
        int pos = atomicAdd(&cur[d], 1);
        col[row_ptr[d] + pos] = src[i];
    }
}

// ---------------- weight prep: W [K][N] fp32 -> Wt_hi/Wt_lo [N][K] bf16 ----------------
__global__ void k_prep_w(const float* __restrict__ W, unsigned short* __restrict__ hi,
                         unsigned short* __restrict__ lo, int K, int N) {
    int i = blockIdx.x * blockDim.x + threadIdx.x;
    if (i >= K * N) return;
    int k = i / N, n = i % N;
    float v = W[i];
    unsigned short h = f2bf(v);
    float r = v - bf2f(h);
    hi[(long)n * K + k] = h;
    lo[(long)n * K + k] = f2bf(r);
}

// ---------------- barrier-free direct-load split-bf16 MFMA GEMM ----------------
// Wave computes 64 rows x (NI*16) cols. A fragments load straight from global
// (row = base + lane&15, k = quad*8..+8) and split to bf16 hi/lo in registers.
// B fragments (pre-transposed bf16 hi/lo, [N][K]) load straight from global (L2-hot).
// No LDS, no barriers: every wave is an independent latency-tolerant stream.
template <int K, int N, int NI>
__global__ __launch_bounds__(256) void k_gemm_direct(
    const float* __restrict__ A, const unsigned short* __restrict__ Bth,
    const unsigned short* __restrict__ Btl, const float* __restrict__ dinv,
    float* __restrict__ Hs, int M) {
    constexpr int CS = N / (16 * NI);  // col strips
    constexpr int NT = K / 32;         // k32 steps
    const int gw = (blockIdx.x * 256 + threadIdx.x) >> 6;
    const int lane = threadIdx.x & 63;
    const int rb = gw / CS;
    const int cs = gw % CS;
    const int row0 = rb * 64;
    if (row0 >= M) return;
    const int m = lane & 15;
    const int quad = lane >> 4;

    bool rowok[4];
    const float* ap[4];
#pragma unroll
    for (int mi = 0; mi < 4; ++mi) {
        rowok[mi] = (row0 + mi * 16) < M;  // M%16==0 -> whole 16-row group valid or not
        int r = rowok[mi] ? (row0 + mi * 16 + m) : 0;
        ap[mi] = A + (long)r * K + quad * 8;
    }
    const unsigned short* bhp[NI];
    const unsigned short* blp[NI];
#pragma unroll
    for (int ni = 0; ni < NI; ++ni) {
        int n = (cs * NI + ni) * 16 + m;
        bhp[ni] = Bth + (long)n * K + quad * 8;
        blp[ni] = Btl + (long)n * K + quad * 8;
    }

    floatx4 acc[4][NI];
#pragma unroll
    for (int mi = 0; mi < 4; ++mi)
#pragma unroll
        for (int ni = 0; ni < NI; ++ni) acc[mi][ni] = (floatx4){0.f, 0.f, 0.f, 0.f};

    float4 cu[4], cv[4], pu[4], pv[4];
    short8 cbh[NI], cbl[NI], pbh[NI], pbl[NI];

#pragma unroll
    for (int mi = 0; mi < 4; ++mi) {
        cu[mi] = make_float4(0.f, 0.f, 0.f, 0.f);
        cv[mi] = make_float4(0.f, 0.f, 0.f, 0.f);
        if (rowok[mi]) {
            cu[mi] = *(const float4*)(ap[mi]);
            cv[mi] = *(const float4*)(ap[mi] + 4);
        }
    }
#pragma unroll
    for (int ni = 0; ni < NI; ++ni) {
        cbh[ni] = *(const short8*)(bhp[ni]);
        cbl[ni] = *(const short8*)(blp[ni]);
    }

    for (int t = 0; t < NT; ++t) {
        // prefetch step t+1 (loads fly during the convert+MFMA below)
        if (t + 1 < NT) {
#pragma unroll
            for (int mi = 0; mi < 4; ++mi) {
                pu[mi] = make_float4(0.f, 0.f, 0.f, 0.f);
                pv[mi] = make_float4(0.f, 0.f, 0.f, 0.f);
                if (rowok[mi]) {
                    pu[mi] = *(const float4*)(ap[mi] + (t + 1) * 32);
                    pv[mi] = *(const float4*)(ap[mi] + (t + 1) * 32 + 4);
                }
            }
#pragma unroll
            for (int ni = 0; ni < NI; ++ni) {
                pbh[ni] = *(const short8*)(bhp[ni] + (t + 1) * 32);
                pbl[ni] = *(const short8*)(blp[ni] + (t + 1) * 32);
            }
        }
        short8 ah[4], al[4];
#pragma unroll
        for (int mi = 0; mi < 4; ++mi) split8(cu[mi], cv[mi], ah[mi], al[mi]);
#pragma unroll
        for (int ni = 0; ni < NI; ++ni) {
#pragma unroll
            for (int mi = 0; mi < 4; ++mi) {
                acc[mi][ni] = __builtin_amdgcn_mfma_f32_16x16x32_bf16(ah[mi], cbh[ni], acc[mi][ni], 0, 0, 0);
                acc[mi][ni] = __builtin_amdgcn_mfma_f32_16x16x32_bf16(ah[mi], cbl[ni], acc[mi][ni], 0, 0, 0);
                acc[mi][ni] = __builtin_amdgcn_mfma_f32_16x16x32_bf16(al[mi], cbh[ni], acc[mi][ni], 0, 0, 0);
            }
        }
        if (t + 1 < NT) {
#pragma unroll
            for (int mi = 0; mi < 4; ++mi) { cu[mi] = pu[mi]; cv[mi] = pv[mi]; }
#pragma unroll
            for (int ni = 0; ni < NI; ++ni) { cbh[ni] = pbh[ni]; cbl[ni] = pbl[ni]; }
        }
    }

    // epilogue: C/D layout col=lane&15, row=quad*4+reg; scale by dinv[row]
#pragma unroll
    for (int mi = 0; mi < 4; ++mi) {
#pragma unroll
        for (int r = 0; r < 4; ++r) {
            int row = row0 + mi * 16 + quad * 4 + r;
            if (row < M) {
                float dv = dinv[row];
#pragma unroll
                for (int ni = 0; ni < NI; ++ni) {
                    int n = (cs * NI + ni) * 16 + m;
                    Hs[(long)row * N + n] = acc[mi][ni][r] * dv;
                }
            }
        }
    }
}

// ---------------- CSR aggregation, wave per node, 4x unrolled gathers ----------------
__global__ __launch_bounds__(256) void k_agg1(
    const float* __restrict__ h, const int* __restrict__ row_ptr,
    const int* __restrict__ col, const float* __restrict__ dinv,
    const float* __restrict__ bias, float* __restrict__ z, int n) {
    int node = blockIdx.x * 4 + (threadIdx.x >> 6);
    node = __builtin_amdgcn_readfirstlane(node);
    if (node >= n) return;
    int lane = threadIdx.x & 63;
    const float2* hp = (const float2*)h;
    float2 acc = hp[(long)node * 64 + lane];  // self-loop
    int rs = row_ptr[node], re = row_ptr[node + 1];
    int j = rs;
    for (; j + 4 <= re; j += 4) {
        int s0 = col[j], s1 = col[j + 1], s2 = col[j + 2], s3 = col[j + 3];
        float2 v0 = hp[(long)s0 * 64 + lane];
        float2 v1 = hp[(long)s1 * 64 + lane];
        float2 v2 = hp[(long)s2 * 64 + lane];
        float2 v3 = hp[(long)s3 * 64 + lane];
        acc.x += v0.x + v1.x + v2.x + v3.x;
        acc.y += v0.y + v1.y + v2.y + v3.y;
    }
    for (; j < re; ++j) {
        int s = col[j];
        float2 v = hp[(long)s * 64 + lane];
        acc.x += v.x;
        acc.y += v.y;
    }
    float dv = dinv[node];
    float2 b = ((const float2*)bias)[lane];
    acc.x = fmaxf(fmaf(acc.x, dv, b.x), 0.f);
    acc.y = fmaxf(fmaf(acc.y, dv, b.y), 0.f);
    ((float2*)z)[(long)node * 64 + lane] = acc;
}

__global__ __launch_bounds__(256) void k_agg2(
    const float* __restrict__ h, const int* __restrict__ row_ptr,
    const int* __restrict__ col, const float* __restrict__ dinv,
    const float* __restrict__ bias, float* __restrict__ z, int n) {
    int node = blockIdx.x * 4 + (threadIdx.x >> 6);
    node = __builtin_amdgcn_readfirstlane(node);
    if (node >= n) return;
    int lane = threadIdx.x & 63;
    float acc = h[(long)node * 64 + lane];  // self-loop
    int rs = row_ptr[node], re = row_ptr[node + 1];
    int j = rs;
    for (; j + 4 <= re; j += 4) {
        int s0 = col[j], s1 = col[j + 1], s2 = col[j + 2], s3 = col[j + 3];
        acc += h[(long)s0 * 64 + lane] + h[(long)s1 * 64 + lane] +
               h[(long)s2 * 64 + lane] + h[(long)s3 * 64 + lane];
    }
    for (; j < re; ++j) acc += h[(long)col[j] * 64 + lane];
    z[(long)node * 64 + lane] = fmaf(acc, dinv[node], bias[lane]);
}

// ---------------- decoder ----------------
__global__ void k_dot(const float* __restrict__ z2, const int* __restrict__ es,
                      const int* __restrict__ ed, float* __restrict__ out, int L) {
    int gid = blockIdx.x * blockDim.x + threadIdx.x;
    int wid = gid >> 6;
    int lane = threadIdx.x & 63;
    if (wid >= L) return;
    int a = es[wid], b = ed[wid];
    float v = z2[(long)a * OUT_C + lane] * z2[(long)b * OUT_C + lane];
#pragma unroll
    for (int off = 32; off > 0; off >>= 1) v += __shfl_down(v, off);
    if (lane == 0) out[wid] = v;
}

extern "C" void kernel_launch(void* const* d_in, const int* in_sizes, int n_in,
                              void* d_out, int out_size, void* d_ws, size_t ws_size,
                              hipStream_t stream) {
    const float* x = (const float*)d_in[0];
    const int* ei = (const int*)d_in[1];
    const int* eli = (const int*)d_in[2];
    const float* W1 = (const float*)d_in[3];
    const float* b1 = (const float*)d_in[4];
    const float* W2 = (const float*)d_in[5];
    const float* b2 = (const float*)d_in[6];
    float* out = (float*)d_out;

    const int N = in_sizes[0] / IN_C;  // 50000
    const int E = in_sizes[1] / 2;     // 800000
    const int L = in_sizes[2] / 2;     // 100000
    const int* src = ei;
    const int* dst = ei + E;
    const int* es = eli;
    const int* ed = eli + L;

    const int Npad = (N + 63) & ~63;
    const int Epad = (E + 3) & ~3;

    // workspace layout (~56 MB)
    int* cnt = (int*)d_ws;             // Npad
    int* cur = cnt + Npad;             // Npad
    int* row_ptr = cur + Npad;         // Npad + 64
    int* bsum = row_ptr + Npad + 64;   // 256
    int* col = bsum + 256;             // Epad
    float* dinv = (float*)(col + Epad);    // Npad
    float* h1s = dinv + Npad;              // N*128
    float* z1 = h1s + (long)N * HID_C;     // N*128
    float* h2s = h1s;                      // alias: h1s dead after agg1
    float* z2 = h1s + (long)N * OUT_C;     // alias: disjoint from h2s
    unsigned short* wt1_hi = (unsigned short*)(z1 + (long)N * HID_C);  // 512*128
    unsigned short* wt1_lo = wt1_hi + IN_C * HID_C;
    unsigned short* wt2_hi = wt1_lo + IN_C * HID_C;                    // 128*64
    unsigned short* wt2_lo = wt2_hi + HID_C * OUT_C;

    const int TPB = 256;
    const int nb = (N + 255) / 256;

    // weight prep
    k_prep_w<<<(IN_C * HID_C + TPB - 1) / TPB, TPB, 0, stream>>>(W1, wt1_hi, wt1_lo, IN_C, HID_C);
    k_prep_w<<<(HID_C * OUT_C + TPB - 1) / TPB, TPB, 0, stream>>>(W2, wt2_hi, wt2_lo, HID_C, OUT_C);

    // CSR build + dinv
    k_zero_int<<<(2 * Npad + TPB - 1) / TPB, TPB, 0, stream>>>(cnt, 2 * Npad);
    k_count<<<(E + TPB - 1) / TPB, TPB, 0, stream>>>(dst, cnt, E);
    k_dinv<<<(N + TPB - 1) / TPB, TPB, 0, stream>>>(cnt, dinv, N);
    k_blocksum<<<nb, 256, 0, stream>>>(cnt, bsum, N);
    k_scanpartials<<<1, 256, 0, stream>>>(bsum, nb);
    k_scanfinal<<<nb, 256, 0, stream>>>(cnt, bsum, row_ptr, N, E);
    k_fill<<<(E + TPB - 1) / TPB, TPB, 0, stream>>>(src, dst, row_ptr, cur, col, E);

    // layer 1: waves = ceil(N/64) * (128/32)
    {
        int waves = ((N + 63) / 64) * (HID_C / 32);
        k_gemm_direct<IN_C, HID_C, 2>
            <<<(waves + 3) / 4, 256, 0, stream>>>(x, wt1_hi, wt1_lo, dinv, h1s, N);
    }
    k_agg1<<<(N + 3) / 4, 256, 0, stream>>>(h1s, row_ptr, col, dinv, b1, z1, N);

    // layer 2: waves = ceil(N/64) * (64/32)
    {
        int waves = ((N + 63) / 64) * (OUT_C / 32);
        k_gemm_direct<HID_C, OUT_C, 2>
            <<<(waves + 3) / 4, 256, 0, stream>>>(z1, wt2_hi, wt2_lo, dinv, h2s, N);
    }
    k_agg2<<<(N + 3) / 4, 256, 0, stream>>>(h2s, row_ptr, col, dinv, b2, z2, N);

    // decoder
    k_dot<<<((long)L * 64 + TPB - 1) / TPB, TPB, 0, stream>>>(z2, es, ed, out, L);
}